// Round 3
// baseline (614.095 us; speedup 1.0000x reference)
//
#include <hip/hip_runtime.h>
#include <cstdint>
#include <cmath>

#define IMG_H 128
#define IMG_W 128
#define TILE 16
#define NSEG 16
#define MARGIN 0.05f

// PROJ constants: computed in double exactly as the Python reference, then cast to f32.
constexpr double FOCAL_D = 140.0, NEAR_D = 0.1, FAR_D = 10.0;
constexpr double RIGHT_D = (IMG_W - 1.0) / 2.0 * NEAR_D / FOCAL_D;
constexpr double TOP_D   = RIGHT_D * ((double)IMG_H / (double)IMG_W);
constexpr float P00 = (float)(NEAR_D / RIGHT_D);
constexpr float P11 = (float)(NEAR_D / TOP_D);
constexpr float P22 = (float)(-(FAR_D + NEAR_D) / (FAR_D - NEAR_D));
constexpr float P32 = (float)(-2.0 * FAR_D * NEAR_D / (FAR_D - NEAR_D));

__device__ __forceinline__ unsigned long long packKey(float z, int f) {
    unsigned int zb = __float_as_uint(z);
    zb = (zb & 0x80000000u) ? ~zb : (zb | 0x80000000u);  // monotone total order
    return ((unsigned long long)zb << 32) | (unsigned int)f;
}

// ---------------- vertex transform: world -> screen (sx, sy, sz, w) ----------------
__global__ void k_vertex(const float* __restrict__ verts, const float* __restrict__ poses,
                         float4* __restrict__ vscr, int B, int N) {
#pragma clang fp contract(off)
    int id = blockIdx.x * blockDim.x + threadIdx.x;
    if (id >= B * N) return;
    int b = id / N;
    const float* v = verts + (size_t)id * 3;
    const float* P = poses + (size_t)b * 16;
    float x = v[0], y = v[1], z = v[2];
    float cp[4][4] = {
        { P[0],  P[1],  P[2],  P[3]  },
        {-P[4], -P[5], -P[6], -P[7]  },
        {-P[8], -P[9], -P[10],-P[11] },
        { P[12], P[13], P[14], P[15] }
    };
    float cam[4];
    for (int j = 0; j < 4; ++j)
        cam[j] = ((x * cp[j][0] + y * cp[j][1]) + z * cp[j][2]) + cp[j][3];
    float c0 = cam[0] * P00;
    float c1 = cam[1] * P11;
    float c2 = (cam[2] * P22) + (cam[3] * P32);
    float c3 = cam[2] * (-1.0f);
    float sx = ((c0 / c3) * 0.5f + 0.5f) * (float)IMG_W;
    float sy = (0.5f - (c1 / c3) * 0.5f) * (float)IMG_H;
    float sz = c2 / c3;
    vscr[id] = make_float4(sx, sy, sz, c3);
}

// ---------------- per-face precompute: edge deltas, z, wok|fid, bbox ----------------
__global__ void k_face(const int* __restrict__ faces, const float4* __restrict__ vscr,
                       float* __restrict__ fdata, float4* __restrict__ fbbox,
                       int B, int N, int F) {
#pragma clang fp contract(off)
    int id = blockIdx.x * blockDim.x + threadIdx.x;
    if (id >= B * F) return;
    int b = id / F; int f = id - b * F;
    int i0 = faces[f * 3 + 0], i1 = faces[f * 3 + 1], i2 = faces[f * 3 + 2];
    float4 v0 = vscr[(size_t)b * N + i0];
    float4 v1 = vscr[(size_t)b * N + i1];
    float4 v2 = vscr[(size_t)b * N + i2];
    float dx0 = v2.x - v1.x, dy0 = v2.y - v1.y;   // e0 anchor (v1)
    float dx1 = v0.x - v2.x, dy1 = v0.y - v2.y;   // e1 anchor (v2)
    float dx2 = v1.x - v0.x, dy2 = v1.y - v0.y;   // e2 anchor (v0)
    bool wok = (v0.w > 1e-6f && v1.w > 1e-6f && v2.w > 1e-6f);
    int enc = wok ? f : (f | 0x80000000);         // sign bit = !wok, low bits = face id
    float* o = fdata + (size_t)id * 16;
    o[0]  = v1.x; o[1]  = v1.y; o[2]  = dx0; o[3]  = dy0;
    o[4]  = v2.x; o[5]  = v2.y; o[6]  = dx1; o[7]  = dy1;
    o[8]  = v0.x; o[9]  = v0.y; o[10] = dx2; o[11] = dy2;
    o[12] = v0.z; o[13] = v1.z; o[14] = v2.z; o[15] = __int_as_float(enc);
    float minx = fminf(v0.x, fminf(v1.x, v2.x));
    float maxx = fmaxf(v0.x, fmaxf(v1.x, v2.x));
    float miny = fminf(v0.y, fminf(v1.y, v2.y));
    float maxy = fmaxf(v0.y, fmaxf(v1.y, v2.y));
    fbbox[id] = make_float4(minx, maxx, miny, maxy);
}

// ---------------- rasterizer: LDS-binned, branchless eval, per-tile/segment ----------------
__global__ __launch_bounds__(256) void k_raster(const float* __restrict__ fdata,
                                                const float4* __restrict__ fbbox,
                                                unsigned long long* __restrict__ keybuf,
                                                int B, int F, int FperSeg) {
#pragma clang fp contract(off)
    __shared__ int s_cnt;
    __shared__ int s_idx[256];
    __shared__ float s_fd[256 * 16];

    int tX = blockIdx.x, tY = blockIdx.y;
    int bz = blockIdx.z;
    int b = bz / NSEG, seg = bz - b * NSEG;
    int tid = threadIdx.x;
    int lx = tid & (TILE - 1), ly = tid >> 4;
    float px = (float)(tX * TILE + lx) + 0.5f;
    float py = (float)(tY * TILE + ly) + 0.5f;
    float tx0 = (float)(tX * TILE) + 0.5f - MARGIN;
    float tx1 = (float)(tX * TILE) + (float)TILE - 0.5f + MARGIN;
    float ty0 = (float)(tY * TILE) + 0.5f - MARGIN;
    float ty1 = (float)(tY * TILE) + (float)TILE - 0.5f + MARGIN;

    int fstart = seg * FperSeg;
    int fend = min(fstart + FperSeg, F);
    unsigned long long best = ~0ull;
    const float4* bb = fbbox + (size_t)b * F;
    const float*  fd = fdata + (size_t)b * F * 16;

    for (int g = fstart; g < fend; g += 256) {
        if (tid == 0) s_cnt = 0;
        __syncthreads();
        // 1) parallel bbox test + LDS compaction
        int f = g + tid;
        if (f < fend) {
            float4 bx = bb[f];  // minx, maxx, miny, maxy
            if ((bx.y >= tx0) && (bx.x <= tx1) && (bx.w >= ty0) && (bx.z <= ty1)) {
                int o = atomicAdd(&s_cnt, 1);
                s_idx[o] = f;
            }
        }
        __syncthreads();
        int nc = s_cnt;
        // 2) cooperative staging: 16 threads load one face's 16 floats (64B coalesced)
        for (int base = 0; base < nc; base += 16) {
            int c = base + (tid >> 4);
            if (c < nc)
                s_fd[c * 16 + (tid & 15)] = fd[(size_t)s_idx[c] * 16 + (tid & 15)];
        }
        __syncthreads();
        // 3) eval loop: branchless, bit-exact edge math; compiler-pipelineable
#pragma unroll 4
        for (int c = 0; c < nc; ++c) {
            const float4* q = (const float4*)(s_fd + c * 16);
            float4 q0 = q[0];  // v1x v1y dx0 dy0
            float4 q1 = q[1];  // v2x v2y dx1 dy1
            float4 q2 = q[2];  // v0x v0y dx2 dy2
            float4 q3 = q[3];  // z0 z1 z2 enc(wok|fid)
            float e0 = q0.z * (py - q0.y) - q0.w * (px - q0.x);
            float e1 = q1.z * (py - q1.y) - q1.w * (px - q1.x);
            float e2 = q2.z * (py - q2.y) - q2.w * (px - q2.x);
            float area = (e0 + e1) + e2;
            bool okA = fabsf(area) > 1e-9f;
            float s = (area > 0.0f) ? 1.0f : ((area < 0.0f) ? -1.0f : area);
            int enc = __float_as_int(q3.w);
            bool inside = (e0 * s >= 0.0f) & (e1 * s >= 0.0f) & (e2 * s >= 0.0f)
                          & okA & (enc >= 0);
            float den = okA ? area : 1.0f;
            float zpix = ((e0 * q3.x + e1 * q3.y) + e2 * q3.z) / den;
            inside = inside & (zpix >= -1.0f) & (zpix <= 1.0f);
            unsigned long long k = inside ? packKey(zpix, enc & 0x7fffffff) : ~0ull;
            best = (k < best) ? k : best;
        }
        __syncthreads();
    }
    if (best != ~0ull)
        atomicMin(&keybuf[((size_t)b * IMG_H + (tY * TILE + ly)) * IMG_W + (tX * TILE + lx)], best);
}

// ---------------- shade + bilinear texture sample ----------------
__global__ void k_shade(const unsigned long long* __restrict__ keybuf,
                        const int* __restrict__ faces, const float4* __restrict__ vscr,
                        const float* __restrict__ uvmap, const float* __restrict__ tex,
                        float* __restrict__ out, int B, int N, int tside) {
#pragma clang fp contract(off)
    int id = blockIdx.x * blockDim.x + threadIdx.x;
    if (id >= B * IMG_H * IMG_W) return;
    int b = id / (IMG_H * IMG_W);
    int p = id - b * (IMG_H * IMG_W);
    int y = p / IMG_W, x = p - y * IMG_W;
    unsigned long long key = keybuf[id];
    int fid = (key == ~0ull) ? -1 : (int)(key & 0xFFFFFFFFull);
    int f = (fid < 0) ? 0 : fid;
    int i0 = faces[f * 3 + 0], i1 = faces[f * 3 + 1], i2 = faces[f * 3 + 2];
    float4 v0 = vscr[(size_t)b * N + i0];
    float4 v1 = vscr[(size_t)b * N + i1];
    float4 v2 = vscr[(size_t)b * N + i2];
    float px = (float)x + 0.5f, py = (float)y + 0.5f;
    float e0 = (v2.x - v1.x) * (py - v1.y) - (v2.y - v1.y) * (px - v1.x);
    float e1 = (v0.x - v2.x) * (py - v2.y) - (v0.y - v2.y) * (px - v2.x);
    float e2 = (v1.x - v0.x) * (py - v0.y) - (v1.y - v0.y) * (px - v0.x);
    float bw0 = e0 / v0.w, bw1 = e1 / v1.w, bw2 = e2 / v2.w;
    float den = (bw0 + bw1) + bw2;
    den = (fabsf(den) > 1e-9f) ? den : 1.0f;
    float pc0 = bw0 / den, pc1 = bw1 / den, pc2 = bw2 / den;
    float u0 = uvmap[((size_t)b * N + i0) * 2],     vv0 = uvmap[((size_t)b * N + i0) * 2 + 1];
    float u1 = uvmap[((size_t)b * N + i1) * 2],     vv1 = uvmap[((size_t)b * N + i1) * 2 + 1];
    float u2 = uvmap[((size_t)b * N + i2) * 2],     vv2 = uvmap[((size_t)b * N + i2) * 2 + 1];
    float g0 = (pc0 * 1.0f + pc1 * 1.0f) + pc2 * 1.0f;
    float g1 = (pc0 * u0 + pc1 * u1) + pc2 * u2;
    float g2 = (pc0 * vv0 + pc1 * vv1) + pc2 * vv2;
    float mask = (fid >= 0) ? 1.0f : 0.0f;
    g0 = g0 * mask; g1 = g1 * mask; g2 = g2 * mask;
    float ts = (float)tside;
    float iyf = fminf(fmaxf(g2, 0.0f), 1.0f) * ts;
    float ixf = fminf(fmaxf(g1, 0.0f), 1.0f) * ts;
    float fly = floorf(iyf), flx = floorf(ixf);
    float fy = iyf - fly, fx = ixf - flx;
    int iy = (int)fly, ix = (int)flx;
    int tmax = tside - 1;
    int iy0 = min(max(iy, 0), tmax),     iy1 = min(max(iy + 1, 0), tmax);
    int ix0 = min(max(ix, 0), tmax),     ix1 = min(max(ix + 1, 0), tmax);
    const float* tb = tex + (size_t)b * tside * tside * 3;
    const float* tl = tb + ((size_t)iy0 * tside + ix0) * 3;
    const float* tr = tb + ((size_t)iy0 * tside + ix1) * 3;
    const float* bl = tb + ((size_t)iy1 * tside + ix0) * 3;
    const float* br = tb + ((size_t)iy1 * tside + ix1) * 3;
    float omfx = 1.0f - fx, omfy = 1.0f - fy;
    float* o = out + (size_t)id * 3;
    for (int c = 0; c < 3; ++c) {
        float r = (((tl[c] * omfx) * omfy) + ((tr[c] * fx) * omfy)) + ((bl[c] * omfx) * fy);
        r = r + ((br[c] * fx) * fy);
        o[c] = r * g0;
    }
}

extern "C" void kernel_launch(void* const* d_in, const int* in_sizes, int n_in,
                              void* d_out, int out_size, void* d_ws, size_t ws_size,
                              hipStream_t stream) {
    const float* verts = (const float*)d_in[0];
    const float* uvmap = (const float*)d_in[1];
    const int*   faces = (const int*)d_in[2];
    const float* tex   = (const float*)d_in[3];
    const float* poses = (const float*)d_in[4];
    int B = in_sizes[4] / 16;
    int N = in_sizes[0] / (B * 3);
    int F = in_sizes[2] / 3;
    int texels = in_sizes[3] / (B * 3);
    int tside = (int)(sqrt((double)texels) + 0.5);

    char* ws = (char*)d_ws;
    float4* vscr = (float4*)ws;
    size_t off = (size_t)B * N * sizeof(float4);
    float* fdata = (float*)(ws + off);  off += (size_t)B * F * 16 * sizeof(float);
    float4* fbbox = (float4*)(ws + off); off += (size_t)B * F * sizeof(float4);
    unsigned long long* keybuf = (unsigned long long*)(ws + off);
    size_t keybytes = (size_t)B * IMG_H * IMG_W * sizeof(unsigned long long);

    hipMemsetAsync(keybuf, 0xFF, keybytes, stream);
    k_vertex<<<(B * N + 255) / 256, 256, 0, stream>>>(verts, poses, vscr, B, N);
    k_face<<<(B * F + 255) / 256, 256, 0, stream>>>(faces, vscr, fdata, fbbox, B, N, F);
    int FperSeg = (F + NSEG - 1) / NSEG;
    dim3 grast(IMG_W / TILE, IMG_H / TILE, B * NSEG);
    k_raster<<<grast, 256, 0, stream>>>(fdata, fbbox, keybuf, B, F, FperSeg);
    k_shade<<<(B * IMG_H * IMG_W + 255) / 256, 256, 0, stream>>>(
        keybuf, faces, vscr, uvmap, tex, (float*)d_out, B, N, tside);
}

// Round 4
// 458.071 us; speedup vs baseline: 1.3406x; 1.3406x over previous
//
#include <hip/hip_runtime.h>
#include <cstdint>
#include <cmath>

#define IMG_H 128
#define IMG_W 128
#define TILE 16
#define NSEG 32
#define MARGIN 0.05f

// PROJ constants: computed in double exactly as the Python reference, then cast to f32.
constexpr double FOCAL_D = 140.0, NEAR_D = 0.1, FAR_D = 10.0;
constexpr double RIGHT_D = (IMG_W - 1.0) / 2.0 * NEAR_D / FOCAL_D;
constexpr double TOP_D   = RIGHT_D * ((double)IMG_H / (double)IMG_W);
constexpr float P00 = (float)(NEAR_D / RIGHT_D);
constexpr float P11 = (float)(NEAR_D / TOP_D);
constexpr float P22 = (float)(-(FAR_D + NEAR_D) / (FAR_D - NEAR_D));
constexpr float P32 = (float)(-2.0 * FAR_D * NEAR_D / (FAR_D - NEAR_D));

__device__ __forceinline__ unsigned long long packKey(float z, int f) {
    unsigned int zb = __float_as_uint(z);
    zb = (zb & 0x80000000u) ? ~zb : (zb | 0x80000000u);  // monotone total order
    return ((unsigned long long)zb << 32) | (unsigned int)f;
}

// ---------------- vertex transform: world -> screen (sx, sy, sz, w) ----------------
__global__ void k_vertex(const float* __restrict__ verts, const float* __restrict__ poses,
                         float4* __restrict__ vscr, int B, int N) {
#pragma clang fp contract(off)
    int id = blockIdx.x * blockDim.x + threadIdx.x;
    if (id >= B * N) return;
    int b = id / N;
    const float* v = verts + (size_t)id * 3;
    const float* P = poses + (size_t)b * 16;
    float x = v[0], y = v[1], z = v[2];
    float cp[4][4] = {
        { P[0],  P[1],  P[2],  P[3]  },
        {-P[4], -P[5], -P[6], -P[7]  },
        {-P[8], -P[9], -P[10],-P[11] },
        { P[12], P[13], P[14], P[15] }
    };
    float cam[4];
    for (int j = 0; j < 4; ++j)
        cam[j] = ((x * cp[j][0] + y * cp[j][1]) + z * cp[j][2]) + cp[j][3];
    float c0 = cam[0] * P00;
    float c1 = cam[1] * P11;
    float c2 = (cam[2] * P22) + (cam[3] * P32);
    float c3 = cam[2] * (-1.0f);
    float sx = ((c0 / c3) * 0.5f + 0.5f) * (float)IMG_W;
    float sy = (0.5f - (c1 / c3) * 0.5f) * (float)IMG_H;
    float sz = c2 / c3;
    vscr[id] = make_float4(sx, sy, sz, c3);
}

// ---------------- per-face precompute: edge deltas, z, wok|fid, bbox ----------------
__global__ void k_face(const int* __restrict__ faces, const float4* __restrict__ vscr,
                       float* __restrict__ fdata, float4* __restrict__ fbbox,
                       int B, int N, int F) {
#pragma clang fp contract(off)
    int id = blockIdx.x * blockDim.x + threadIdx.x;
    if (id >= B * F) return;
    int b = id / F; int f = id - b * F;
    int i0 = faces[f * 3 + 0], i1 = faces[f * 3 + 1], i2 = faces[f * 3 + 2];
    float4 v0 = vscr[(size_t)b * N + i0];
    float4 v1 = vscr[(size_t)b * N + i1];
    float4 v2 = vscr[(size_t)b * N + i2];
    float dx0 = v2.x - v1.x, dy0 = v2.y - v1.y;   // e0 anchor (v1)
    float dx1 = v0.x - v2.x, dy1 = v0.y - v2.y;   // e1 anchor (v2)
    float dx2 = v1.x - v0.x, dy2 = v1.y - v0.y;   // e2 anchor (v0)
    bool wok = (v0.w > 1e-6f && v1.w > 1e-6f && v2.w > 1e-6f);
    int enc = wok ? f : (f | 0x80000000);         // sign bit = !wok, low bits = face id
    float* o = fdata + (size_t)id * 16;
    o[0]  = v1.x; o[1]  = v1.y; o[2]  = dx0; o[3]  = dy0;
    o[4]  = v2.x; o[5]  = v2.y; o[6]  = dx1; o[7]  = dy1;
    o[8]  = v0.x; o[9]  = v0.y; o[10] = dx2; o[11] = dy2;
    o[12] = v0.z; o[13] = v1.z; o[14] = v2.z; o[15] = __int_as_float(enc);
    float minx = fminf(v0.x, fminf(v1.x, v2.x));
    float maxx = fmaxf(v0.x, fmaxf(v1.x, v2.x));
    float miny = fminf(v0.y, fminf(v1.y, v2.y));
    float maxy = fmaxf(v0.y, fmaxf(v1.y, v2.y));
    fbbox[id] = make_float4(minx, maxx, miny, maxy);
}

// ---------------- rasterizer: LDS-binned, band-masked, per-tile/segment ----------------
__global__ __launch_bounds__(256) void k_raster(const float* __restrict__ fdata,
                                                const float4* __restrict__ fbbox,
                                                unsigned long long* __restrict__ keybuf,
                                                int B, int F, int FperSeg) {
#pragma clang fp contract(off)
    __shared__ int s_cnt;
    __shared__ int s_idx[256];           // bits 0..23: face id, bits 24..27: wave band mask
    __shared__ float s_fd[256 * 16];

    int tX = blockIdx.x, tY = blockIdx.y;
    int bz = blockIdx.z;
    int b = bz / NSEG, seg = bz - b * NSEG;
    int tid = threadIdx.x;
    int lx = tid & (TILE - 1), ly = tid >> 4;
    float px = (float)(tX * TILE + lx) + 0.5f;
    float py = (float)(tY * TILE + ly) + 0.5f;
    float tx0 = (float)(tX * TILE) + 0.5f - MARGIN;
    float tx1 = (float)(tX * TILE) + (float)TILE - 0.5f + MARGIN;
    float ty0 = (float)(tY * TILE) + 0.5f - MARGIN;
    float ty1 = (float)(tY * TILE) + (float)TILE - 0.5f + MARGIN;
    int wv = tid >> 6;                   // wave index: owns rows [wv*4, wv*4+3] of tile
    int wbit = 1 << (24 + wv);

    int fstart = seg * FperSeg;
    int fend = min(fstart + FperSeg, F);
    unsigned long long best = ~0ull;
    const float4* bb = fbbox + (size_t)b * F;
    const float*  fd = fdata + (size_t)b * F * 16;

    for (int g = fstart; g < fend; g += 256) {
        if (tid == 0) s_cnt = 0;
        __syncthreads();
        // 1) parallel bbox test + LDS compaction, with per-wave 4-row band mask
        int f = g + tid;
        if (f < fend) {
            float4 bx = bb[f];  // minx, maxx, miny, maxy
            if ((bx.y >= tx0) && (bx.x <= tx1) && (bx.w >= ty0) && (bx.z <= ty1)) {
                int bm = 0;
                for (int wvi = 0; wvi < 4; ++wvi) {
                    float blo = (float)(tY * TILE + wvi * 4) + 0.5f - MARGIN;
                    float bhi = blo + 3.0f + 2.0f * MARGIN;
                    if (!(bx.w < blo || bx.z > bhi)) bm |= (1 << wvi);
                }
                int o = atomicAdd(&s_cnt, 1);
                s_idx[o] = f | (bm << 24);
            }
        }
        __syncthreads();
        int nc = s_cnt;
        // 2) cooperative staging: 16 threads load one face's 16 floats (64B coalesced)
        for (int base = 0; base < nc; base += 16) {
            int c = base + (tid >> 4);
            if (c < nc)
                s_fd[c * 16 + (tid & 15)] = fd[(size_t)(s_idx[c] & 0xFFFFFF) * 16 + (tid & 15)];
        }
        __syncthreads();
        // 3) eval loop: cheap wave-uniform band skip, bit-exact edge math, ballot-guarded div
        for (int c = 0; c < nc; ++c) {
            int meta = s_idx[c];
            if (!(meta & wbit)) continue;          // this wave's 4 rows can't be inside
            const float4* q = (const float4*)(s_fd + c * 16);
            float4 q0 = q[0];  // v1x v1y dx0 dy0
            float4 q1 = q[1];  // v2x v2y dx1 dy1
            float4 q2 = q[2];  // v0x v0y dx2 dy2
            float4 q3 = q[3];  // z0 z1 z2 enc(wok|fid)
            float e0 = q0.z * (py - q0.y) - q0.w * (px - q0.x);
            float e1 = q1.z * (py - q1.y) - q1.w * (px - q1.x);
            float e2 = q2.z * (py - q2.y) - q2.w * (px - q2.x);
            float area = (e0 + e1) + e2;
            bool okA = fabsf(area) > 1e-9f;
            float s = (area > 0.0f) ? 1.0f : ((area < 0.0f) ? -1.0f : area);
            int enc = __float_as_int(q3.w);
            bool inside = (e0 * s >= 0.0f) && (e1 * s >= 0.0f) && (e2 * s >= 0.0f)
                          && okA && (enc >= 0);
            if (__ballot(inside)) {
                float den = okA ? area : 1.0f;
                float zpix = ((e0 * q3.x + e1 * q3.y) + e2 * q3.z) / den;
                if (inside && (zpix >= -1.0f) && (zpix <= 1.0f)) {
                    unsigned long long k = packKey(zpix, enc);
                    best = (k < best) ? k : best;
                }
            }
        }
        __syncthreads();
    }
    if (best != ~0ull)
        atomicMin(&keybuf[((size_t)b * IMG_H + (tY * TILE + ly)) * IMG_W + (tX * TILE + lx)], best);
}

// ---------------- shade + bilinear texture sample ----------------
__global__ void k_shade(const unsigned long long* __restrict__ keybuf,
                        const int* __restrict__ faces, const float4* __restrict__ vscr,
                        const float* __restrict__ uvmap, const float* __restrict__ tex,
                        float* __restrict__ out, int B, int N, int tside) {
#pragma clang fp contract(off)
    int id = blockIdx.x * blockDim.x + threadIdx.x;
    if (id >= B * IMG_H * IMG_W) return;
    int b = id / (IMG_H * IMG_W);
    int p = id - b * (IMG_H * IMG_W);
    int y = p / IMG_W, x = p - y * IMG_W;
    unsigned long long key = keybuf[id];
    int fid = (key == ~0ull) ? -1 : (int)(key & 0xFFFFFFFFull);
    int f = (fid < 0) ? 0 : fid;
    int i0 = faces[f * 3 + 0], i1 = faces[f * 3 + 1], i2 = faces[f * 3 + 2];
    float4 v0 = vscr[(size_t)b * N + i0];
    float4 v1 = vscr[(size_t)b * N + i1];
    float4 v2 = vscr[(size_t)b * N + i2];
    float px = (float)x + 0.5f, py = (float)y + 0.5f;
    float e0 = (v2.x - v1.x) * (py - v1.y) - (v2.y - v1.y) * (px - v1.x);
    float e1 = (v0.x - v2.x) * (py - v2.y) - (v0.y - v2.y) * (px - v2.x);
    float e2 = (v1.x - v0.x) * (py - v0.y) - (v1.y - v0.y) * (px - v0.x);
    float bw0 = e0 / v0.w, bw1 = e1 / v1.w, bw2 = e2 / v2.w;
    float den = (bw0 + bw1) + bw2;
    den = (fabsf(den) > 1e-9f) ? den : 1.0f;
    float pc0 = bw0 / den, pc1 = bw1 / den, pc2 = bw2 / den;
    float u0 = uvmap[((size_t)b * N + i0) * 2],     vv0 = uvmap[((size_t)b * N + i0) * 2 + 1];
    float u1 = uvmap[((size_t)b * N + i1) * 2],     vv1 = uvmap[((size_t)b * N + i1) * 2 + 1];
    float u2 = uvmap[((size_t)b * N + i2) * 2],     vv2 = uvmap[((size_t)b * N + i2) * 2 + 1];
    float g0 = (pc0 * 1.0f + pc1 * 1.0f) + pc2 * 1.0f;
    float g1 = (pc0 * u0 + pc1 * u1) + pc2 * u2;
    float g2 = (pc0 * vv0 + pc1 * vv1) + pc2 * vv2;
    float mask = (fid >= 0) ? 1.0f : 0.0f;
    g0 = g0 * mask; g1 = g1 * mask; g2 = g2 * mask;
    float ts = (float)tside;
    float iyf = fminf(fmaxf(g2, 0.0f), 1.0f) * ts;
    float ixf = fminf(fmaxf(g1, 0.0f), 1.0f) * ts;
    float fly = floorf(iyf), flx = floorf(ixf);
    float fy = iyf - fly, fx = ixf - flx;
    int iy = (int)fly, ix = (int)flx;
    int tmax = tside - 1;
    int iy0 = min(max(iy, 0), tmax),     iy1 = min(max(iy + 1, 0), tmax);
    int ix0 = min(max(ix, 0), tmax),     ix1 = min(max(ix + 1, 0), tmax);
    const float* tb = tex + (size_t)b * tside * tside * 3;
    const float* tl = tb + ((size_t)iy0 * tside + ix0) * 3;
    const float* tr = tb + ((size_t)iy0 * tside + ix1) * 3;
    const float* bl = tb + ((size_t)iy1 * tside + ix0) * 3;
    const float* br = tb + ((size_t)iy1 * tside + ix1) * 3;
    float omfx = 1.0f - fx, omfy = 1.0f - fy;
    float* o = out + (size_t)id * 3;
    for (int c = 0; c < 3; ++c) {
        float r = (((tl[c] * omfx) * omfy) + ((tr[c] * fx) * omfy)) + ((bl[c] * omfx) * fy);
        r = r + ((br[c] * fx) * fy);
        o[c] = r * g0;
    }
}

extern "C" void kernel_launch(void* const* d_in, const int* in_sizes, int n_in,
                              void* d_out, int out_size, void* d_ws, size_t ws_size,
                              hipStream_t stream) {
    const float* verts = (const float*)d_in[0];
    const float* uvmap = (const float*)d_in[1];
    const int*   faces = (const int*)d_in[2];
    const float* tex   = (const float*)d_in[3];
    const float* poses = (const float*)d_in[4];
    int B = in_sizes[4] / 16;
    int N = in_sizes[0] / (B * 3);
    int F = in_sizes[2] / 3;
    int texels = in_sizes[3] / (B * 3);
    int tside = (int)(sqrt((double)texels) + 0.5);

    char* ws = (char*)d_ws;
    float4* vscr = (float4*)ws;
    size_t off = (size_t)B * N * sizeof(float4);
    float* fdata = (float*)(ws + off);  off += (size_t)B * F * 16 * sizeof(float);
    float4* fbbox = (float4*)(ws + off); off += (size_t)B * F * sizeof(float4);
    unsigned long long* keybuf = (unsigned long long*)(ws + off);
    size_t keybytes = (size_t)B * IMG_H * IMG_W * sizeof(unsigned long long);

    hipMemsetAsync(keybuf, 0xFF, keybytes, stream);
    k_vertex<<<(B * N + 255) / 256, 256, 0, stream>>>(verts, poses, vscr, B, N);
    k_face<<<(B * F + 255) / 256, 256, 0, stream>>>(faces, vscr, fdata, fbbox, B, N, F);
    int FperSeg = (F + NSEG - 1) / NSEG;
    dim3 grast(IMG_W / TILE, IMG_H / TILE, B * NSEG);
    k_raster<<<grast, 256, 0, stream>>>(fdata, fbbox, keybuf, B, F, FperSeg);
    k_shade<<<(B * IMG_H * IMG_W + 255) / 256, 256, 0, stream>>>(
        keybuf, faces, vscr, uvmap, tex, (float*)d_out, B, N, tside);
}

// Round 5
// 389.953 us; speedup vs baseline: 1.5748x; 1.1747x over previous
//
#include <hip/hip_runtime.h>
#include <cstdint>
#include <cmath>

#define IMG_H 128
#define IMG_W 128

// PROJ constants: computed in double exactly as the Python reference, then cast to f32.
constexpr double FOCAL_D = 140.0, NEAR_D = 0.1, FAR_D = 10.0;
constexpr double RIGHT_D = (IMG_W - 1.0) / 2.0 * NEAR_D / FOCAL_D;
constexpr double TOP_D   = RIGHT_D * ((double)IMG_H / (double)IMG_W);
constexpr float P00 = (float)(NEAR_D / RIGHT_D);
constexpr float P11 = (float)(NEAR_D / TOP_D);
constexpr float P22 = (float)(-(FAR_D + NEAR_D) / (FAR_D - NEAR_D));
constexpr float P32 = (float)(-2.0 * FAR_D * NEAR_D / (FAR_D - NEAR_D));

__device__ __forceinline__ unsigned long long packKey(float z, int f) {
    unsigned int zb = __float_as_uint(z);
    zb = (zb & 0x80000000u) ? ~zb : (zb | 0x80000000u);  // monotone total order
    return ((unsigned long long)zb << 32) | (unsigned int)f;
}

// ---------------- vertex transform: world -> screen (sx, sy, sz, w) ----------------
__global__ void k_vertex(const float* __restrict__ verts, const float* __restrict__ poses,
                         float4* __restrict__ vscr, int B, int N) {
#pragma clang fp contract(off)
    int id = blockIdx.x * blockDim.x + threadIdx.x;
    if (id >= B * N) return;
    int b = id / N;
    const float* v = verts + (size_t)id * 3;
    const float* P = poses + (size_t)b * 16;
    float x = v[0], y = v[1], z = v[2];
    float cp[4][4] = {
        { P[0],  P[1],  P[2],  P[3]  },
        {-P[4], -P[5], -P[6], -P[7]  },
        {-P[8], -P[9], -P[10],-P[11] },
        { P[12], P[13], P[14], P[15] }
    };
    float cam[4];
    for (int j = 0; j < 4; ++j)
        cam[j] = ((x * cp[j][0] + y * cp[j][1]) + z * cp[j][2]) + cp[j][3];
    float c0 = cam[0] * P00;
    float c1 = cam[1] * P11;
    float c2 = (cam[2] * P22) + (cam[3] * P32);
    float c3 = cam[2] * (-1.0f);
    float sx = ((c0 / c3) * 0.5f + 0.5f) * (float)IMG_W;
    float sy = (0.5f - (c1 / c3) * 0.5f) * (float)IMG_H;
    float sz = c2 / c3;
    vscr[id] = make_float4(sx, sy, sz, c3);
}

// ---------------- rasterizer: ONE WAVE PER FACE, 8x8 lane-tiles over face bbox ----------------
__global__ __launch_bounds__(256) void k_rasterF(const int* __restrict__ faces,
                                                 const float4* __restrict__ vscr,
                                                 unsigned long long* __restrict__ keybuf,
                                                 int B, int N, int F) {
#pragma clang fp contract(off)
    int wid = __builtin_amdgcn_readfirstlane(blockIdx.x * 4 + (threadIdx.x >> 6));
    if (wid >= B * F) return;
    int b = wid / F;
    int f = wid - b * F;
    int lane = threadIdx.x & 63;

    int i0 = faces[f * 3 + 0], i1 = faces[f * 3 + 1], i2 = faces[f * 3 + 2];
    float4 v0 = vscr[(size_t)b * N + i0];
    float4 v1 = vscr[(size_t)b * N + i1];
    float4 v2 = vscr[(size_t)b * N + i2];

    // wok: reference sets ok=false if any w <= 1e-6 -> face contributes nothing
    if (!(v0.w > 1e-6f && v1.w > 1e-6f && v2.w > 1e-6f)) return;

    // edge deltas, identical expressions/order to reference
    float dx0 = v2.x - v1.x, dy0 = v2.y - v1.y;   // e0 anchor (v1)
    float dx1 = v0.x - v2.x, dy1 = v0.y - v2.y;   // e1 anchor (v2)
    float dx2 = v1.x - v0.x, dy2 = v1.y - v0.y;   // e2 anchor (v0)
    float z0 = v0.z, z1 = v1.z, z2 = v2.z;

    float minx = fminf(v0.x, fminf(v1.x, v2.x));
    float maxx = fmaxf(v0.x, fmaxf(v1.x, v2.x));
    float miny = fminf(v0.y, fminf(v1.y, v2.y));
    float maxy = fmaxf(v0.y, fmaxf(v1.y, v2.y));
    // NaN guard (reference: NaN edge fns -> inside false everywhere)
    if (!(minx <= maxx) || !(miny <= maxy)) return;
    // clamp to sane range before int conversion (huge coords from tiny w)
    minx = fmaxf(minx, -4.0f);  maxx = fminf(maxx, (float)IMG_W + 4.0f);
    miny = fmaxf(miny, -4.0f);  maxy = fminf(maxy, (float)IMG_H + 4.0f);
    // pixel index range with >=1px guard band for edge-fn rounding slack
    int xlo = max(0, (int)floorf(minx) - 1);
    int xhi = min(IMG_W - 1, (int)floorf(maxx) + 1);
    int ylo = max(0, (int)floorf(miny) - 1);
    int yhi = min(IMG_H - 1, (int)floorf(maxy) + 1);
    if (xlo > xhi || ylo > yhi) return;

    int lx = lane & 7, lyn = lane >> 3;
    unsigned long long* kb = keybuf + (size_t)b * IMG_H * IMG_W;

    for (int y0 = ylo; y0 <= yhi; y0 += 8) {
        int y = y0 + lyn;
        bool yok = (y <= yhi);
        float py = (float)y + 0.5f;
        float pyd0 = py - v1.y, pyd1 = py - v2.y, pyd2 = py - v0.y;
        for (int x0 = xlo; x0 <= xhi; x0 += 8) {
            int x = x0 + lx;
            bool ok = yok && (x <= xhi);
            float px = (float)x + 0.5f;
            // bit-exact reference op order (contract off)
            float e0 = dx0 * pyd0 - dy0 * (px - v1.x);
            float e1 = dx1 * pyd1 - dy1 * (px - v2.x);
            float e2 = dx2 * pyd2 - dy2 * (px - v0.x);
            float area = (e0 + e1) + e2;
            bool okA = fabsf(area) > 1e-9f;
            float s = (area > 0.0f) ? 1.0f : ((area < 0.0f) ? -1.0f : area);
            bool inside = (e0 * s >= 0.0f) && (e1 * s >= 0.0f) && (e2 * s >= 0.0f)
                          && okA && ok;
            if (__ballot(inside)) {
                float den = okA ? area : 1.0f;
                float zpix = ((e0 * z0 + e1 * z1) + e2 * z2) / den;
                if (inside && (zpix >= -1.0f) && (zpix <= 1.0f)) {
                    unsigned long long* ap = &kb[(size_t)y * IMG_W + x];
                    unsigned long long cur = *(const volatile unsigned long long*)ap;
                    unsigned long long k = packKey(zpix, f);
                    if (k < cur) atomicMin(ap, k);   // filter: stale cur is only ever larger -> safe
                }
            }
        }
    }
}

// ---------------- shade + bilinear texture sample ----------------
__global__ void k_shade(const unsigned long long* __restrict__ keybuf,
                        const int* __restrict__ faces, const float4* __restrict__ vscr,
                        const float* __restrict__ uvmap, const float* __restrict__ tex,
                        float* __restrict__ out, int B, int N, int tside) {
#pragma clang fp contract(off)
    int id = blockIdx.x * blockDim.x + threadIdx.x;
    if (id >= B * IMG_H * IMG_W) return;
    int b = id / (IMG_H * IMG_W);
    int p = id - b * (IMG_H * IMG_W);
    int y = p / IMG_W, x = p - y * IMG_W;
    unsigned long long key = keybuf[id];
    int fid = (key == ~0ull) ? -1 : (int)(key & 0xFFFFFFFFull);
    int f = (fid < 0) ? 0 : fid;
    int i0 = faces[f * 3 + 0], i1 = faces[f * 3 + 1], i2 = faces[f * 3 + 2];
    float4 v0 = vscr[(size_t)b * N + i0];
    float4 v1 = vscr[(size_t)b * N + i1];
    float4 v2 = vscr[(size_t)b * N + i2];
    float px = (float)x + 0.5f, py = (float)y + 0.5f;
    float e0 = (v2.x - v1.x) * (py - v1.y) - (v2.y - v1.y) * (px - v1.x);
    float e1 = (v0.x - v2.x) * (py - v2.y) - (v0.y - v2.y) * (px - v2.x);
    float e2 = (v1.x - v0.x) * (py - v0.y) - (v1.y - v0.y) * (px - v0.x);
    float bw0 = e0 / v0.w, bw1 = e1 / v1.w, bw2 = e2 / v2.w;
    float den = (bw0 + bw1) + bw2;
    den = (fabsf(den) > 1e-9f) ? den : 1.0f;
    float pc0 = bw0 / den, pc1 = bw1 / den, pc2 = bw2 / den;
    float u0 = uvmap[((size_t)b * N + i0) * 2],     vv0 = uvmap[((size_t)b * N + i0) * 2 + 1];
    float u1 = uvmap[((size_t)b * N + i1) * 2],     vv1 = uvmap[((size_t)b * N + i1) * 2 + 1];
    float u2 = uvmap[((size_t)b * N + i2) * 2],     vv2 = uvmap[((size_t)b * N + i2) * 2 + 1];
    float g0 = (pc0 * 1.0f + pc1 * 1.0f) + pc2 * 1.0f;
    float g1 = (pc0 * u0 + pc1 * u1) + pc2 * u2;
    float g2 = (pc0 * vv0 + pc1 * vv1) + pc2 * vv2;
    float mask = (fid >= 0) ? 1.0f : 0.0f;
    g0 = g0 * mask; g1 = g1 * mask; g2 = g2 * mask;
    float ts = (float)tside;
    float iyf = fminf(fmaxf(g2, 0.0f), 1.0f) * ts;
    float ixf = fminf(fmaxf(g1, 0.0f), 1.0f) * ts;
    float fly = floorf(iyf), flx = floorf(ixf);
    float fy = iyf - fly, fx = ixf - flx;
    int iy = (int)fly, ix = (int)flx;
    int tmax = tside - 1;
    int iy0 = min(max(iy, 0), tmax),     iy1 = min(max(iy + 1, 0), tmax);
    int ix0 = min(max(ix, 0), tmax),     ix1 = min(max(ix + 1, 0), tmax);
    const float* tb = tex + (size_t)b * tside * tside * 3;
    const float* tl = tb + ((size_t)iy0 * tside + ix0) * 3;
    const float* tr = tb + ((size_t)iy0 * tside + ix1) * 3;
    const float* bl = tb + ((size_t)iy1 * tside + ix0) * 3;
    const float* br = tb + ((size_t)iy1 * tside + ix1) * 3;
    float omfx = 1.0f - fx, omfy = 1.0f - fy;
    float* o = out + (size_t)id * 3;
    for (int c = 0; c < 3; ++c) {
        float r = (((tl[c] * omfx) * omfy) + ((tr[c] * fx) * omfy)) + ((bl[c] * omfx) * fy);
        r = r + ((br[c] * fx) * fy);
        o[c] = r * g0;
    }
}

extern "C" void kernel_launch(void* const* d_in, const int* in_sizes, int n_in,
                              void* d_out, int out_size, void* d_ws, size_t ws_size,
                              hipStream_t stream) {
    const float* verts = (const float*)d_in[0];
    const float* uvmap = (const float*)d_in[1];
    const int*   faces = (const int*)d_in[2];
    const float* tex   = (const float*)d_in[3];
    const float* poses = (const float*)d_in[4];
    int B = in_sizes[4] / 16;
    int N = in_sizes[0] / (B * 3);
    int F = in_sizes[2] / 3;
    int texels = in_sizes[3] / (B * 3);
    int tside = (int)(sqrt((double)texels) + 0.5);

    char* ws = (char*)d_ws;
    float4* vscr = (float4*)ws;
    size_t off = (size_t)B * N * sizeof(float4);
    unsigned long long* keybuf = (unsigned long long*)(ws + off);
    size_t keybytes = (size_t)B * IMG_H * IMG_W * sizeof(unsigned long long);

    hipMemsetAsync(keybuf, 0xFF, keybytes, stream);
    k_vertex<<<(B * N + 255) / 256, 256, 0, stream>>>(verts, poses, vscr, B, N);
    int nwaves = B * F;
    k_rasterF<<<(nwaves + 3) / 4, 256, 0, stream>>>(faces, vscr, keybuf, B, N, F);
    k_shade<<<(B * IMG_H * IMG_W + 255) / 256, 256, 0, stream>>>(
        keybuf, faces, vscr, uvmap, tex, (float*)d_out, B, N, tside);
}